// Round 9
// baseline (205.656 us; speedup 1.0000x reference)
//
#include <hip/hip_runtime.h>

namespace {

constexpr int HH  = 48;
constexpr int DIM = 384;
constexpr int NH  = 6;
constexpr int K3  = 27;
constexpr float L2E    = 1.44269504088896f;
constexpr float SCALE2 = 0.125f * L2E;          // 64^-0.5 * log2(e)

constexpr int TT     = 4;
constexpr int NPAD   = 224;
constexpr int TILES1 = HH / TT;                 // 12
constexpr int TILES  = TILES1 * TILES1 * TILES1;// 1728
constexpr int NBLK   = 2 * NH * TILES;          // 20736 (div by 8)

typedef _Float16 half8  __attribute__((ext_vector_type(8)));
typedef _Float16 half4v __attribute__((ext_vector_type(4)));
typedef _Float16 half2v __attribute__((ext_vector_type(2)));
typedef __fp16   fp16x2 __attribute__((ext_vector_type(2)));
typedef float    floatx4 __attribute__((ext_vector_type(4)));

__device__ __forceinline__ half2v pk(float a, float b) {
    fp16x2 t = __builtin_amdgcn_cvt_pkrtz(a, b);
    return __builtin_bit_cast(half2v, t);
}

// GEMM + banded scatter for one wave covering nt in [NT0, NT0+NTC)
template<int NT0, int NTC>
__device__ __forceinline__ void gemm_scatter(
    const char* kl, float* logit_lds, half8 a0, half8 a1,
    int mtile, int lrow, int lgrp)
{
    const int cbase = mtile * 36 + lrow;
    const int xm2 = (cbase & 7) << 4;                 // invariant under +16 cols
    const char* bpA = kl + cbase * 128 + ((lgrp * 16) ^ xm2);
    const char* bpB = kl + cbase * 128 + ((lgrp * 16 + 64) ^ xm2);
    floatx4 acc[NTC];
    #pragma unroll
    for (int j = 0; j < NTC; ++j) {
        const int nt = NT0 + j;
        const half8 b0 = *(const half8*)(bpA + nt * 2048);
        const half8 b1 = *(const half8*)(bpB + nt * 2048);
        floatx4 c = {0.f, 0.f, 0.f, 0.f};
        c = __builtin_amdgcn_mfma_f32_16x16x32_f16(a0, b0, c, 0, 0, 0);
        c = __builtin_amdgcn_mfma_f32_16x16x32_f16(a1, b1, c, 0, 0, 0);
        acc[j] = c;
    }
    // rel = nt*16+lrow = rx*36+ry*6+rz; query row m=(mtile,lgrp,r):
    // di=rx, dj=ry-lgrp, dl=rz-r; slot=(di*3+dj)*3+dl
    const int ly6 = lrow >= 12 ? 2 : (lrow >= 6 ? 1 : 0);
    const int lz6 = lrow - ly6 * 6;
    const int base0 = (mtile * 16 + lgrp * 4) * 112;  // byte offset of row m(r=0)
    constexpr int Nx[7] = {0, 0, 0, 1, 1, 2, 2};
    constexpr int Ny[7] = {0, 2, 5, 2, 4, 1, 4};
    constexpr int Nz[7] = {0, 4, 2, 0, 4, 2, 0};
    #pragma unroll
    for (int j = 0; j < NTC; ++j) {
        const int nt = NT0 + j;
        int rz = lz6 + Nz[nt];
        int ry = ly6 + Ny[nt];
        if (rz >= 6) { rz -= 6; ry += 1; }
        int rx = Nx[nt];
        if (ry >= 6) { ry -= 6; rx += 1; }
        const int dj = ry - lgrp;
        if (rx <= 2 && (unsigned)dj <= 2u) {
            const int sl0 = (rx * 3 + dj) * 3 + rz;   // slot(r) = sl0 - r
            #pragma unroll
            for (int r = 0; r < 4; ++r) {
                if ((unsigned)(rz - r) <= 2u) {
                    *(float*)((char*)logit_lds + base0 + r * 112 + (sl0 - r) * 4)
                        = acc[j][r];
                }
            }
        }
    }
}

__global__ __launch_bounds__(512, 6)
void natten_mfma7(const float* __restrict__ q, const float* __restrict__ k,
                  const float* __restrict__ rpb, const float* __restrict__ vv,
                  float* __restrict__ out)
{
    __shared__ _Float16 k_lds[NPAD * 64];    // 28672 B, swizzled
    __shared__ float    logit_lds[64 * 28];  //  7168 B
    __shared__ float4   rv_lds[K3];          //   432 B   total 36272 B

    const int bid0 = blockIdx.x;
    const int bid  = (bid0 & 7) * (NBLK / 8) + (bid0 >> 3);   // bijective XCD swizzle

    const int n    = bid % NH;                 // head-fastest for L2 sharing
    const int tile = (bid / NH) % TILES;
    const int b    = bid / (NH * TILES);
    const int tz = (tile % TILES1) * TT;
    const int ty = ((tile / TILES1) % TILES1) * TT;
    const int tx = (tile / (TILES1 * TILES1)) * TT;

    const int tid = threadIdx.x;
    char* kl = (char*)k_lds;

    if (tid < K3) {      // compiler-tracked loads; drained before the asm region
        rv_lds[tid] = make_float4(vv[tid * 3], vv[tid * 3 + 1], vv[tid * 3 + 2],
                                  rpb[n * K3 + tid] * L2E);
    }

    const int w = tid >> 6, lane = tid & 63;
    const int lrow = lane & 15, lgrp = lane >> 4;
    const int mtile = w >> 1, h = w & 1;       // wave-pair: M-tile, column half

    // ============ phase A: issue all 11 VMEM loads per thread via asm ============
    const float* qp = q + (size_t)b * (HH * HH * HH) * DIM
        + (size_t)(((tx + mtile) * 48 + (ty + (lrow >> 2))) * 48 + (tz + (lrow & 3))) * DIM
        + n * 64 + lgrp * 8;
    floatx4 qf0, qf1, qg0, qg1;
    asm volatile(
        "global_load_dwordx4 %0, %4, off\n\t"
        "global_load_dwordx4 %1, %4, off offset:16\n\t"
        "global_load_dwordx4 %2, %4, off offset:128\n\t"
        "global_load_dwordx4 %3, %4, off offset:144"
        : "=&v"(qf0), "=&v"(qf1), "=&v"(qg0), "=&v"(qg1)
        : "v"(qp) : "memory");

    // k: 512 threads, 16B chunks; col0 = tid>>4 in [0,32), ch = tid&15.
    // col = col0 + 32*it (7 iters covers 224 cols), 16B f32 -> 8B f16.
    const float* kb = k + (size_t)b * (HH * HH * HH) * DIM + n * 64;
    const int col0 = tid >> 4;
    const int ch   = tid & 15;
    char* dst = kl + col0 * 128 + ((ch * 8) ^ ((col0 & 7) << 4));   // col&7 invariant

    floatx4 F[7];
    float   MS[7];
    {
        int cx = 0, cy = col0 / 6, cz = col0 - (col0 / 6) * 6;
        #pragma unroll
        for (int it = 0; it < 7; ++it) {
            const int gx = tx + cx - 1, gy = ty + cy - 1, gz = tz + cz - 1;
            const bool valid = ((unsigned)gx < 48u) && ((unsigned)gy < 48u) &&
                               ((unsigned)gz < 48u);
            const int cgx = min(max(gx, 0), 47);
            const int cgy = min(max(gy, 0), 47);
            const int cgz = min(max(gz, 0), 47);
            const float* s = kb + (size_t)((cgx * 48 + cgy) * 48 + cgz) * DIM + ch * 4;
            asm volatile("global_load_dwordx4 %0, %1, off"
                         : "=&v"(F[it]) : "v"(s) : "memory");
            MS[it] = valid ? 1.f : 0.f;
            cz += 2; if (cz >= 6) { cz -= 6; cy += 1; }     // +32 = (0,5,2) base-6
            cy += 5; if (cy >= 6) { cy -= 6; cx += 1; }
        }
    }

    // single drain; all 11 payload quads tied so converts depend on it
    asm volatile("s_waitcnt vmcnt(0)"
        : "+v"(qf0), "+v"(qf1), "+v"(qg0), "+v"(qg1),
          "+v"(F[0]), "+v"(F[1]), "+v"(F[2]), "+v"(F[3]),
          "+v"(F[4]), "+v"(F[5]), "+v"(F[6])
        ::);
    __builtin_amdgcn_sched_barrier(0);

    // ============ phase B: convert + LDS write ============
    #pragma unroll
    for (int it = 0; it < 7; ++it) {
        const float m = MS[it];
        half4v hv;
        ((half2v*)&hv)[0] = pk(F[it][0] * m, F[it][1] * m);
        ((half2v*)&hv)[1] = pk(F[it][2] * m, F[it][3] * m);
        *(half4v*)(dst + it * 4096) = hv;
    }

    half8 a0, a1;
    ((half2v*)&a0)[0] = pk(qf0[0], qf0[1]);
    ((half2v*)&a0)[1] = pk(qf0[2], qf0[3]);
    ((half2v*)&a0)[2] = pk(qf1[0], qf1[1]);
    ((half2v*)&a0)[3] = pk(qf1[2], qf1[3]);
    ((half2v*)&a1)[0] = pk(qg0[0], qg0[1]);
    ((half2v*)&a1)[1] = pk(qg0[2], qg0[3]);
    ((half2v*)&a1)[2] = pk(qg1[0], qg1[1]);
    ((half2v*)&a1)[3] = pk(qg1[2], qg1[3]);
    __syncthreads();

    // ============ GEMM + scatter: wave-pair splits cols [m*36, m*36+112) ========
    if (h == 0) {
        gemm_scatter<0, 4>(kl, logit_lds, a0, a1, mtile, lrow, lgrp);
    } else {
        gemm_scatter<4, 3>(kl, logit_lds, a0, a1, mtile, lrow, lgrp);
    }
    __syncthreads();    // logit rows assembled by wave-pairs

    // ============ softmax (exp2 domain): 4 threads/query, waves 0-3 ============
    if (tid < 256) {
        const int qi = tid >> 2, p = tid & 3;
        const float* lp = logit_lds + qi * 28;
        float t[7];
        float mx = -1e30f;
        #pragma unroll
        for (int j = 0; j < 7; ++j) {
            const int o = p + 4 * j;
            if (o < K3) {
                t[j] = fmaf(lp[o], SCALE2, rv_lds[o].w);
                mx = fmaxf(mx, t[j]);
            }
        }
        mx = fmaxf(mx, __shfl_xor(mx, 1));
        mx = fmaxf(mx, __shfl_xor(mx, 2));
        float den = 0.f, n0 = 0.f, n1 = 0.f, n2 = 0.f;
        #pragma unroll
        for (int j = 0; j < 7; ++j) {
            const int o = p + 4 * j;
            if (o < K3) {
                const float e = __builtin_amdgcn_exp2f(t[j] - mx);
                const float4 rv = rv_lds[o];
                den += e;
                n0 = fmaf(e, rv.x, n0);
                n1 = fmaf(e, rv.y, n1);
                n2 = fmaf(e, rv.z, n2);
            }
        }
        den += __shfl_xor(den, 1); den += __shfl_xor(den, 2);
        n0  += __shfl_xor(n0, 1);  n0  += __shfl_xor(n0, 2);
        n1  += __shfl_xor(n1, 1);  n1  += __shfl_xor(n1, 2);
        n2  += __shfl_xor(n2, 1);  n2  += __shfl_xor(n2, 2);
        if (p < 3) {
            const float res = (p == 0 ? n0 : (p == 1 ? n1 : n2)) / den;
            out[((size_t)(b * 18 + n * 3 + p) * HH + (tx + (qi >> 4))) * (size_t)(HH * HH)
                + (size_t)(ty + ((qi >> 2) & 3)) * HH + (tz + (qi & 3))] = res;
        }
    }
}

} // namespace

extern "C" void kernel_launch(void* const* d_in, const int* in_sizes, int n_in,
                              void* d_out, int out_size, void* d_ws, size_t ws_size,
                              hipStream_t stream)
{
    (void)in_sizes; (void)n_in; (void)d_ws; (void)ws_size; (void)out_size;
    const float* q   = (const float*)d_in[0];
    const float* k   = (const float*)d_in[1];
    const float* rpb = (const float*)d_in[2];
    const float* vv  = (const float*)d_in[3];
    float* out = (float*)d_out;

    natten_mfma7<<<dim3(NBLK), dim3(512), 0, stream>>>(q, k, rpb, vv, out);
}